// Round 6
// baseline (875.907 us; speedup 1.0000x reference)
//
#include <hip/hip_runtime.h>
#include <math.h>

// TransPhormer equivariant graph attention — round 6.
// vs r5: edges additionally sorted by SRC; new k_logit runs src-major with the
// node's qk row held in registers (loaded once, sequentially) -> eliminates
// k_agg's 633 MB random qk[src] HBM gather. k_agg consumes precomputed logits.
// cp layout (240): [0,48) = cp0 ; 48 + u*3 + c = cp1[u][c]
// qk layout per node: qkbuf[n*1920 + i*64 + lane], lane=(hh=lane&7, rr=lane>>3),
//   element = qk[hh][J=rr*30+i]; J<48 scalar, else u=(J-48)/3, c=(J-48)%3.

constexpr float EPSV        = 1e-5f;
constexpr float INV_SQRT3   = 0.5773502691896258f;
constexpr float INV_SQRT2   = 0.7071067811865476f;
constexpr float INV_SQRT32  = 0.17677669529663687f;
constexpr float INV_SQRT48  = 0.14433756729740643f;
constexpr float INV_SQRT128 = 0.08838834764831845f;
constexpr float SCALE_ATT   = 0.14433756729740643f; // 1/sqrt(48)

#define LDS_FENCE() do { asm volatile("s_waitcnt lgkmcnt(0)" ::: "memory"); \
                         __builtin_amdgcn_sched_barrier(0); } while (0)

__device__ __forceinline__ float wsum64(float v) {
#pragma unroll
  for (int m = 1; m < 64; m <<= 1) v += __shfl_xor(v, m);
  return v;
}

__device__ __forceinline__ unsigned bf16r(float f) {
  unsigned b = __float_as_uint(f);
  return (b + 0x7FFFu + ((b >> 16) & 1u)) >> 16;
}

// ---------------- sort machinery (dst-sort AND src-sort, merged passes) -------
__global__ void init_count(unsigned* __restrict__ count, unsigned* __restrict__ count2,
                           int N) {
  int i = blockIdx.x * blockDim.x + threadIdx.x;
  if (i < N) { count[i] = 0u; count2[i] = 0u; }
}

__global__ void k_hist(const int* __restrict__ edge_index,
                       unsigned* __restrict__ count_dst,
                       unsigned* __restrict__ count_src, int E) {
  int e = blockIdx.x * blockDim.x + threadIdx.x;
  if (e < E) {
    atomicAdd(&count_dst[edge_index[(size_t)E + e]], 1u);
    atomicAdd(&count_src[edge_index[e]], 1u);
  }
}

// blockIdx 0: dst arrays, blockIdx 1: src arrays (parallel scans)
__global__ __launch_bounds__(1024) void k_scan2(
    const unsigned* __restrict__ c0, unsigned* __restrict__ o0, unsigned* __restrict__ u0,
    const unsigned* __restrict__ c1, unsigned* __restrict__ o1, unsigned* __restrict__ u1,
    int N) {
  const unsigned* count = blockIdx.x ? c1 : c0;
  unsigned* offs   = blockIdx.x ? o1 : o0;
  unsigned* cursor = blockIdx.x ? u1 : u0;
  __shared__ unsigned buf[1024];
  __shared__ unsigned carry;
  if (threadIdx.x == 0) carry = 0u;
  __syncthreads();
  for (int base = 0; base < N; base += 1024) {
    int i = base + threadIdx.x;
    unsigned v = (i < N) ? count[i] : 0u;
    buf[threadIdx.x] = v;
    __syncthreads();
    for (int off = 1; off < 1024; off <<= 1) {
      unsigned t = (threadIdx.x >= (unsigned)off) ? buf[threadIdx.x - off] : 0u;
      __syncthreads();
      buf[threadIdx.x] += t;
      __syncthreads();
    }
    unsigned excl = buf[threadIdx.x] - v + carry;
    if (i < N) { offs[i] = excl; cursor[i] = excl; }
    __syncthreads();
    if (threadIdx.x == 1023) carry += buf[1023];
    __syncthreads();
  }
  if (threadIdx.x == 0) offs[N] = carry;
}

__global__ void k_scatter(const int* __restrict__ edge_index,
                          unsigned* __restrict__ cursor, unsigned* __restrict__ sorted,
                          unsigned* __restrict__ cursor2, unsigned* __restrict__ sorted2,
                          int E) {
  int e = blockIdx.x * blockDim.x + threadIdx.x;
  if (e < E) {
    unsigned p0 = atomicAdd(&cursor[edge_index[(size_t)E + e]], 1u);
    sorted[p0] = (unsigned)e;
    unsigned p1 = atomicAdd(&cursor2[edge_index[e]], 1u);
    sorted2[p1] = (unsigned)e;
  }
}

// ---------------- fold q-projection into key weights ----------------
__global__ __launch_bounds__(256) void k_wfold(
    const float* __restrict__ Wq0, const float* __restrict__ Wq1,
    const float* __restrict__ Wkv0, const float* __restrict__ Wkv1,
    unsigned* __restrict__ WATp, unsigned* __restrict__ WBTp) {
  int idx = blockIdx.x * 256 + threadIdx.x;
  if (idx < 32 * 384) {
    int k2 = idx / 384, o = idx % 384;
    int h = o / 48, j = o % 48;
    const float* wq0 = Wq0 + (size_t)(2 * k2) * 256 + h * 32;
    const float* wq1 = Wq0 + (size_t)(2 * k2 + 1) * 256 + h * 32;
    const float* wk  = Wkv0 + (size_t)j * 512 + h * 32;
    float s0 = 0.f, s1 = 0.f;
#pragma unroll
    for (int m = 0; m < 32; m++) { s0 += wq0[m] * wk[m]; s1 += wq1[m] * wk[m]; }
    s0 *= 0.125f * INV_SQRT48; s1 *= 0.125f * INV_SQRT48;
    WATp[idx] = bf16r(s0) | (bf16r(s1) << 16);
  }
  idx -= 32 * 384;
  if (idx >= 0 && idx < 16 * 512) {
    int u2 = idx / 512, o2 = idx % 512;
    int h = o2 / 64, u = o2 % 64;
    const float* wa = Wq1 + (size_t)(2 * u2) * 128 + h * 16;
    const float* wb = Wq1 + (size_t)(2 * u2 + 1) * 128 + h * 16;
    const float* wk = Wkv1 + (size_t)u * 256 + h * 16;
    float s0 = 0.f, s1 = 0.f;
#pragma unroll
    for (int t = 0; t < 16; t++) { s0 += wa[t] * wk[t]; s1 += wb[t] * wk[t]; }
    s0 *= 0.125f * INV_SQRT32; s1 *= 0.125f * INV_SQRT32;
    WBTp[idx] = bf16r(s0) | (bf16r(s1) << 16);
  }
}

// ---------------- node-side: norms + qk (folded) + s/d, 16 nodes/block --------
__global__ __launch_bounds__(256) void k_node(
    const float* __restrict__ node, const float* __restrict__ gamma0,
    const float* __restrict__ gamma1,
    const unsigned* __restrict__ WATp, const unsigned* __restrict__ WBTp,
    const float* __restrict__ Wsrc0, const float* __restrict__ Wsrc1,
    const float* __restrict__ Wdst0, const float* __restrict__ Wdst1,
    float* __restrict__ qkbuf, float* __restrict__ sbuf, float* __restrict__ dbuf,
    int N) {
  __shared__ unsigned WATL[32 * 384];   // 49152 B
  __shared__ unsigned WBTL[16 * 512];   // 32768 B
  __shared__ float    hL[16][160];      // 10240 B
  __shared__ float    Wsd0L[64 * 64];   // 16384 B
  __shared__ float    Wsd1L[32 * 32];   // 4096 B

  int t = threadIdx.x;
  for (int i = t; i < 32 * 384; i += 256) WATL[i] = WATp[i];
  for (int i = t; i < 16 * 512; i += 256) WBTL[i] = WBTp[i];
  for (int i = t; i < 64 * 64; i += 256) {
    int k = i >> 6, o3 = i & 63, wh = o3 >> 5, j = o3 & 31;
    Wsd0L[i] = (wh ? Wdst0 : Wsrc0)[k * 32 + j];
  }
  for (int i = t; i < 32 * 32; i += 256) {
    int u = i >> 5, o4 = i & 31, wh = o4 >> 4, v = o4 & 15;
    Wsd1L[i] = (wh ? Wdst1 : Wsrc1)[u * 16 + v];
  }

  int wid = t >> 6, lane = t & 63;
  int n0 = blockIdx.x * 16;
  int nmax = min(16, N - n0);
  if (nmax <= 0) return;

  for (int nl = wid * 4; nl < min(wid * 4 + 4, nmax); nl++) {
    const float* nrow = node + (size_t)(n0 + nl) * 160;
    float v0 = nrow[lane];
    float mu = wsum64(v0) * (1.0f / 64.0f);
    float dv = v0 - mu;
    float var = wsum64(dv * dv) * (1.0f / 64.0f);
    float rs0 = rsqrtf(var + EPSV);
    float a = nrow[64 + lane];
    float b = (lane < 32) ? nrow[128 + lane] : 0.0f;
    float vn = wsum64(a * a + b * b) * (1.0f / 32.0f);
    float rs1 = rsqrtf(vn + EPSV);
    hL[nl][lane] = dv * rs0 * gamma0[lane];
    hL[nl][64 + lane] = a * rs1 * gamma1[lane / 3];
    if (lane < 32) hL[nl][128 + lane] = b * rs1 * gamma1[(64 + lane) / 3];
  }
  __syncthreads();

  int hh = lane & 7, rr = lane >> 3;
  int i0 = t >> 6;
  for (int s = 0; s < 8; s++) {
    int i = i0 + 4 * s;
    if (i >= 30) break;
    int J = rr * 30 + i;
    float acc[16];
#pragma unroll
    for (int n = 0; n < 16; n++) acc[n] = 0.f;
    if (J < 48) {
      int o = hh * 48 + J;
#pragma unroll 2
      for (int k2 = 0; k2 < 32; k2++) {
        unsigned pr = WATL[k2 * 384 + o];
        float w0 = __uint_as_float(pr << 16);
        float w1 = __uint_as_float(pr & 0xFFFF0000u);
#pragma unroll
        for (int n = 0; n < 16; n++) {
          float2 hp = *reinterpret_cast<const float2*>(&hL[n][2 * k2]);
          acc[n] += hp.x * w0 + hp.y * w1;
        }
      }
    } else {
      int u = (J - 48) / 3, c = (J - 48) - 3 * u;
      int o2 = hh * 64 + u;
#pragma unroll 2
      for (int u2 = 0; u2 < 16; u2++) {
        unsigned pr = WBTL[u2 * 512 + o2];
        float w0 = __uint_as_float(pr << 16);
        float w1 = __uint_as_float(pr & 0xFFFF0000u);
#pragma unroll
        for (int n = 0; n < 16; n++)
          acc[n] += hL[n][64 + (2 * u2) * 3 + c] * w0 +
                    hL[n][64 + (2 * u2 + 1) * 3 + c] * w1;
      }
    }
    for (int n = 0; n < nmax; n++)
      qkbuf[(size_t)(n0 + n) * 1920 + i * 64 + lane] = acc[n];
  }

  if (t < 64) {
    int wh = t >> 5, j = t & 31;
    float acc[16];
#pragma unroll
    for (int n = 0; n < 16; n++) acc[n] = 0.f;
    for (int k = 0; k < 64; k++) {
      float w = Wsd0L[k * 64 + t];
#pragma unroll
      for (int n = 0; n < 16; n++) acc[n] += hL[n][k] * w;
    }
    float* obuf = wh ? dbuf : sbuf;
    for (int n = 0; n < nmax; n++) obuf[(size_t)(n0 + n) * 80 + j] = acc[n] * 0.125f;
  } else if (t < 160) {
    int idx = t - 64;
    int wh = idx / 48, vc = idx % 48, v = vc / 3, c = vc - 3 * v;
    float acc[16];
#pragma unroll
    for (int n = 0; n < 16; n++) acc[n] = 0.f;
    for (int u = 0; u < 32; u++) {
      float w = Wsd1L[u * 32 + wh * 16 + v];
#pragma unroll
      for (int n = 0; n < 16; n++) acc[n] += hL[n][64 + u * 3 + c] * w;
    }
    float* obuf = wh ? dbuf : sbuf;
    for (int n = 0; n < nmax; n++)
      obuf[(size_t)(n0 + n) * 80 + 32 + vc] = acc[n] * INV_SQRT32;
  }
}

// ---------------- src-major logit pass: qk row in registers ----------------
__global__ __launch_bounds__(256, 4) void k_logit(
    const float* __restrict__ rbf, const float* __restrict__ rsh,
    const int* __restrict__ edge_index,
    const float* __restrict__ W_rbf,
    const float* __restrict__ qkbuf, const float* __restrict__ sbuf,
    const float* __restrict__ dbuf,
    const unsigned* __restrict__ offs2, const unsigned* __restrict__ sorted2,
    float* __restrict__ logits, int N, int E) {
  __shared__ float S[4 * 432];   // per wave: x 80 | w 112 | cp 240
  int tid = threadIdx.x, wid = tid >> 6, lane = tid & 63;
  int hh = lane & 7, rr = lane >> 3;
  float* xw  = S + wid * 432;
  float* ww  = xw + 80;
  float* cpL = xw + 192;

  int n = blockIdx.x * 4 + wid;
  if (n >= N) return;
  unsigned off = offs2[n];
  int deg = (int)(offs2[n + 1] - off);
  if (deg == 0) return;

  // this node's qk row: sequential coalesced load
  float qkv[30];
  const float* qkr = qkbuf + (size_t)n * 1920;
#pragma unroll
  for (int i = 0; i < 30; i++) qkv[i] = qkr[i * 64 + lane];
  float sx0 = sbuf[(size_t)n * 80 + lane];
  float sx1 = (lane < 16) ? sbuf[(size_t)n * 80 + 64 + lane] : 0.f;

  unsigned e = sorted2[off];
  int dst = edge_index[(size_t)E + e];
  for (int t = 0; t < deg; t++) {
    unsigned e_next = 0; int dst_next = 0;
    if (t + 1 < deg) { e_next = sorted2[off + t + 1]; dst_next = edge_index[(size_t)E + e_next]; }

    float dx0 = dbuf[(size_t)dst * 80 + lane];
    float dx1 = (lane < 16) ? dbuf[(size_t)dst * 80 + 64 + lane] : 0.f;
    xw[lane] = sx0 + dx0;
    if (lane < 16) xw[64 + lane] = sx1 + dx1;
    const float* rrow = rbf + (size_t)e * 16;
    for (int j = lane; j < 112; j += 64) {
      float acw = 0.f;
#pragma unroll
      for (int k = 0; k < 16; k++) acw += rrow[k] * W_rbf[k * 112 + j];
      ww[j] = acw;
    }
    LDS_FENCE();

    float y0 = rsh[(size_t)e * 4], ya = rsh[(size_t)e * 4 + 1];
    float yb = rsh[(size_t)e * 4 + 2], yc = rsh[(size_t)e * 4 + 3];
    if (lane < 48) {
      float v;
      if (lane < 32) v = ww[lane] * xw[lane] * y0;
      else {
        int u = lane - 32;
        float dp = xw[32 + u * 3] * ya + xw[32 + u * 3 + 1] * yb + xw[32 + u * 3 + 2] * yc;
        v = ww[32 + u] * dp * INV_SQRT3;
      }
      cpL[lane] = v;
    }
    {
      int u = lane; float c0, c1, c2;
      if (u < 32) {
        float aw = ww[48 + u] * xw[u];
        c0 = aw * ya; c1 = aw * yb; c2 = aw * yc;
      } else if (u < 48) {
        int t2 = u - 32; float wv = ww[80 + t2] * y0;
        c0 = wv * xw[32 + t2 * 3]; c1 = wv * xw[32 + t2 * 3 + 1]; c2 = wv * xw[32 + t2 * 3 + 2];
      } else {
        int t2 = u - 48;
        float x0 = xw[32 + t2 * 3], x1 = xw[32 + t2 * 3 + 1], x2 = xw[32 + t2 * 3 + 2];
        float wv = ww[96 + t2] * INV_SQRT2;
        c0 = wv * (x1 * yc - x2 * yb);
        c1 = wv * (x2 * ya - x0 * yc);
        c2 = wv * (x0 * yb - x1 * ya);
      }
      cpL[48 + u * 3] = c0; cpL[48 + u * 3 + 1] = c1; cpL[48 + u * 3 + 2] = c2;
    }
    LDS_FENCE();

    float part = 0.f;
#pragma unroll
    for (int i = 0; i < 30; i++) part += qkv[i] * cpL[rr * 30 + i];
    part += __shfl_xor(part, 8);
    part += __shfl_xor(part, 16);
    part += __shfl_xor(part, 32);
    if (rr == 0) logits[(size_t)e * 8 + hh] = part * SCALE_ATT;
    LDS_FENCE();
    e = e_next; dst = dst_next;
  }
}

// ---------------- dst-major: online-softmax aggregation + value GEMM ----------
__global__ __launch_bounds__(256, 5) void k_agg(
    const float* __restrict__ rbf, const float* __restrict__ rsh,
    const int* __restrict__ edge_index,
    const float* __restrict__ W_rbf, const float* __restrict__ Wkv0,
    const float* __restrict__ Wkv1,
    const float* __restrict__ sbuf, const float* __restrict__ dbuf,
    const float* __restrict__ logits,
    const unsigned* __restrict__ offs, const unsigned* __restrict__ sorted,
    float* __restrict__ mlbuf, int N, int E) {
  __shared__ float S[4 * 1952];   // per wave: scratch (432) overlapped by acp (1928)
  int tid = threadIdx.x, wid = tid >> 6, lane = tid & 63;
  int hh = lane & 7, rr = lane >> 3;
  float* acpL = S + wid * 1952;
  float* xw   = acpL;          // 80
  float* ww   = acpL + 80;     // 112
  float* cpL  = acpL + 192;    // 240

  int n = blockIdx.x * 4 + wid;
  if (n >= N) return;
  unsigned off = offs[n];
  int deg = (int)(offs[n + 1] - off);
  float* mlrow = mlbuf + (size_t)n * 640;
  if (deg == 0) {
#pragma unroll
    for (int g = 0; g < 10; g++) mlrow[g * 64 + lane] = 0.f;
    return;
  }

  float xd0 = dbuf[(size_t)n * 80 + lane];
  float xd1 = (lane < 16) ? dbuf[(size_t)n * 80 + 64 + lane] : 0.f;

  float m = -3.4e38f, z = 0.f;
  float acc[30];
#pragma unroll
  for (int i = 0; i < 30; i++) acc[i] = 0.f;

  unsigned e = sorted[off];
  int src = edge_index[e];
  float lg = logits[(size_t)e * 8 + hh];
  for (int t = 0; t < deg; t++) {
    unsigned e_next = 0; int src_next = 0; float lg_next = 0.f;
    if (t + 1 < deg) {
      e_next = sorted[off + t + 1];
      src_next = edge_index[e_next];
      lg_next = logits[(size_t)e_next * 8 + hh];
    }

    const float* srow = sbuf + (size_t)src * 80;
    float sx0 = srow[lane];
    float sx1 = (lane < 16) ? srow[64 + lane] : 0.f;
    xw[lane] = sx0 + xd0;
    if (lane < 16) xw[64 + lane] = sx1 + xd1;
    const float* rrow = rbf + (size_t)e * 16;
    for (int j = lane; j < 112; j += 64) {
      float acw = 0.f;
#pragma unroll
      for (int k = 0; k < 16; k++) acw += rrow[k] * W_rbf[k * 112 + j];
      ww[j] = acw;
    }
    LDS_FENCE();

    float y0 = rsh[(size_t)e * 4], ya = rsh[(size_t)e * 4 + 1];
    float yb = rsh[(size_t)e * 4 + 2], yc = rsh[(size_t)e * 4 + 3];
    if (lane < 48) {
      float v;
      if (lane < 32) v = ww[lane] * xw[lane] * y0;
      else {
        int u = lane - 32;
        float dp = xw[32 + u * 3] * ya + xw[32 + u * 3 + 1] * yb + xw[32 + u * 3 + 2] * yc;
        v = ww[32 + u] * dp * INV_SQRT3;
      }
      cpL[lane] = v;
    }
    {
      int u = lane; float c0, c1, c2;
      if (u < 32) {
        float aw = ww[48 + u] * xw[u];
        c0 = aw * ya; c1 = aw * yb; c2 = aw * yc;
      } else if (u < 48) {
        int t2 = u - 32; float wv = ww[80 + t2] * y0;
        c0 = wv * xw[32 + t2 * 3]; c1 = wv * xw[32 + t2 * 3 + 1]; c2 = wv * xw[32 + t2 * 3 + 2];
      } else {
        int t2 = u - 48;
        float x0 = xw[32 + t2 * 3], x1 = xw[32 + t2 * 3 + 1], x2 = xw[32 + t2 * 3 + 2];
        float wv = ww[96 + t2] * INV_SQRT2;
        c0 = wv * (x1 * yc - x2 * yb);
        c1 = wv * (x2 * ya - x0 * yc);
        c2 = wv * (x0 * yb - x1 * ya);
      }
      cpL[48 + u * 3] = c0; cpL[48 + u * 3 + 1] = c1; cpL[48 + u * 3 + 2] = c2;
    }
    LDS_FENCE();

    // online softmax update with precomputed logit
    float mn = fmaxf(m, lg);
    float sc = expf(m - mn);
    float aa = expf(lg - mn);
    z = z * sc + aa;
#pragma unroll
    for (int i = 0; i < 30; i++) acc[i] = acc[i] * sc + aa * cpL[rr * 30 + i];
    m = mn;
    LDS_FENCE();
    e = e_next; src = src_next; lg = lg_next;
  }

  // stage acp (overlaps dead scratch)
#pragma unroll
  for (int i = 0; i < 30; i++) acpL[hh * 241 + rr * 30 + i] = acc[i];
  LDS_FENCE();

  // value GEMM + normalize
#pragma unroll
  for (int g = 0; g < 4; g++) {
    int col = g * 64 + lane;       // h*32+m
    int h2 = col >> 5;
    float a2 = 0.f;
#pragma unroll
    for (int k = 0; k < 48; k++) a2 += acpL[h2 * 241 + k] * Wkv0[k * 512 + 256 + col];
    float zz = __shfl(z, h2);
    mlrow[col] = a2 * INV_SQRT48 / (zz + 1e-16f);
  }
#pragma unroll
  for (int g = 0; g < 6; g++) {
    int pc = g * 64 + lane;        // p*3+c, p = h*16+u
    int p = pc / 3, c = pc - p * 3;
    int h2 = p >> 4;
    float a2 = 0.f;
#pragma unroll
    for (int w = 0; w < 64; w++)
      a2 += acpL[h2 * 241 + 48 + w * 3 + c] * Wkv1[w * 256 + 128 + p];
    float zz = __shfl(z, h2);
    mlrow[256 + pc] = a2 * 0.125f / (zz + 1e-16f);
  }
}

// ---------------- output projection + residual ----------------
__global__ __launch_bounds__(256) void k_out(
    const float* __restrict__ node, const float* __restrict__ mlbuf,
    const float* __restrict__ Wmsg0, const float* __restrict__ Wmsg1,
    float* __restrict__ out, int N) {
  __shared__ float mlw[4][640];
  int tid = threadIdx.x, wid = tid >> 6, lane = tid & 63;
  int n = blockIdx.x * 4 + wid;
  if (n >= N) return;
  const float* mlrow = mlbuf + (size_t)n * 640;
#pragma unroll
  for (int g = 0; g < 10; g++) mlw[wid][g * 64 + lane] = mlrow[g * 64 + lane];
  LDS_FENCE();
  const float* nrow = node + (size_t)n * 160;
  float* orow = out + (size_t)n * 160;
  {
    float a2 = 0.f;
#pragma unroll 8
    for (int j = 0; j < 256; j++) a2 += mlw[wid][j] * Wmsg0[j * 64 + lane];
    orow[lane] = nrow[lane] + a2 * 0.0625f;
  }
#pragma unroll
  for (int i0 = 0; i0 < 96; i0 += 64) {
    int i = i0 + lane;
    if (i < 96) {
      int v = i / 3, c = i - v * 3;
      float a2 = 0.f;
#pragma unroll 8
      for (int p = 0; p < 128; p++) a2 += mlw[wid][256 + p * 3 + c] * Wmsg1[p * 32 + v];
      orow[64 + i] = nrow[64 + i] + a2 * INV_SQRT128;
    }
  }
}

extern "C" void kernel_launch(void* const* d_in, const int* in_sizes, int n_in,
                              void* d_out, int out_size, void* d_ws, size_t ws_size,
                              hipStream_t stream) {
  (void)n_in; (void)out_size; (void)ws_size;
  const float* node   = (const float*)d_in[0];
  const float* rbf    = (const float*)d_in[1];
  const float* rsh    = (const float*)d_in[2];
  const int*   eidx   = (const int*)d_in[3];
  const float* gamma0 = (const float*)d_in[4];
  const float* gamma1 = (const float*)d_in[5];
  const float* Wq0    = (const float*)d_in[6];
  const float* Wq1    = (const float*)d_in[7];
  const float* Wsrc0  = (const float*)d_in[8];
  const float* Wsrc1  = (const float*)d_in[9];
  const float* Wdst0  = (const float*)d_in[10];
  const float* Wdst1  = (const float*)d_in[11];
  const float* W_rbf  = (const float*)d_in[12];
  const float* Wkv0   = (const float*)d_in[13];
  const float* Wkv1   = (const float*)d_in[14];
  const float* Wmsg0  = (const float*)d_in[15];
  const float* Wmsg1  = (const float*)d_in[16];
  float* out = (float*)d_out;

  int N = in_sizes[0] / 160;
  int E = in_sizes[3] / 2;

  unsigned* WATp = (unsigned*)d_ws;                       // 32*384
  unsigned* WBTp = WATp + 32 * 384;                       // 16*512
  float* sbuf   = (float*)(WBTp + 16 * 512);              // N*80
  float* dbuf   = sbuf + (size_t)N * 80;                  // N*80
  float* qkbuf  = dbuf + (size_t)N * 80;                  // N*1920
  float* mlbuf  = qkbuf + (size_t)N * 1920;               // N*640
  float* logits = mlbuf + (size_t)N * 640;                // E*8
  unsigned* count   = (unsigned*)(logits + (size_t)E * 8);  // N
  unsigned* offs    = count + N;                            // N+1
  unsigned* cursor  = offs + N + 1;                         // N
  unsigned* sorted  = cursor + N;                           // E
  unsigned* count2  = sorted + E;                           // N
  unsigned* offs2   = count2 + N;                           // N+1
  unsigned* cursor2 = offs2 + N + 1;                        // N
  unsigned* sorted2 = cursor2 + N;                          // E

  hipLaunchKernelGGL(init_count, dim3((N + 255) / 256), dim3(256), 0, stream,
                     count, count2, N);
  hipLaunchKernelGGL(k_hist, dim3((E + 255) / 256), dim3(256), 0, stream,
                     eidx, count, count2, E);
  hipLaunchKernelGGL(k_scan2, dim3(2), dim3(1024), 0, stream,
                     count, offs, cursor, count2, offs2, cursor2, N);
  hipLaunchKernelGGL(k_scatter, dim3((E + 255) / 256), dim3(256), 0, stream,
                     eidx, cursor, sorted, cursor2, sorted2, E);
  hipLaunchKernelGGL(k_wfold, dim3(80), dim3(256), 0, stream,
                     Wq0, Wq1, Wkv0, Wkv1, WATp, WBTp);
  hipLaunchKernelGGL(k_node, dim3((N + 15) / 16), dim3(256), 0, stream,
                     node, gamma0, gamma1, WATp, WBTp, Wsrc0, Wsrc1, Wdst0, Wdst1,
                     qkbuf, sbuf, dbuf, N);
  hipLaunchKernelGGL(k_logit, dim3((N + 3) / 4), dim3(256), 0, stream,
                     rbf, rsh, eidx, W_rbf, qkbuf, sbuf, dbuf,
                     offs2, sorted2, logits, N, E);
  hipLaunchKernelGGL(k_agg, dim3((N + 3) / 4), dim3(256), 0, stream,
                     rbf, rsh, eidx, W_rbf, Wkv0, Wkv1, sbuf, dbuf, logits,
                     offs, sorted, mlbuf, N, E);
  hipLaunchKernelGGL(k_out, dim3((N + 3) / 4), dim3(256), 0, stream,
                     node, mlbuf, Wmsg0, Wmsg1, out, N);
}

// Round 7
// 734.618 us; speedup vs baseline: 1.1923x; 1.1923x over previous
//
#include <hip/hip_runtime.h>
#include <math.h>

// TransPhormer equivariant graph attention — round 7.
// vs r6: per-edge tensor product cp computed ENTIRELY in registers with an
// owner-computes layout (lane u owns cp0[u] (u<48) and cp1[u][c]); W_rbf
// columns per lane are fixed (colA=u / colB=48+u) and preloaded. The edge
// loops in k_logit/k_agg have NO LDS and NO fences -> compiler can pipeline
// edges; softmax is two-pass (new k_max kernel) to kill the serial rescale.
// qk layout per node (unchanged): qkbuf[n*1920 + i*64 + lane'],
//   lane'=(hh=lane'&7, rr=lane'>>3), element qk[hh][J=rr*30+i].
// Inverse: (h,J) lives at (J%30)*64 + (J/30)*8 + h.

constexpr float EPSV        = 1e-5f;
constexpr float INV_SQRT3   = 0.5773502691896258f;
constexpr float INV_SQRT2   = 0.7071067811865476f;
constexpr float INV_SQRT32  = 0.17677669529663687f;
constexpr float INV_SQRT48  = 0.14433756729740643f;
constexpr float INV_SQRT128 = 0.08838834764831845f;
constexpr float SCALE_ATT   = 0.14433756729740643f; // 1/sqrt(48)

#define LDS_FENCE() do { asm volatile("s_waitcnt lgkmcnt(0)" ::: "memory"); \
                         __builtin_amdgcn_sched_barrier(0); } while (0)

__device__ __forceinline__ float wsum64(float v) {
#pragma unroll
  for (int m = 1; m < 64; m <<= 1) v += __shfl_xor(v, m);
  return v;
}

__device__ __forceinline__ unsigned bf16r(float f) {
  unsigned b = __float_as_uint(f);
  return (b + 0x7FFFu + ((b >> 16) & 1u)) >> 16;
}

// ---------------- sort machinery (dst-sort AND src-sort) ----------------
__global__ void init_count(unsigned* __restrict__ count, unsigned* __restrict__ count2,
                           int N) {
  int i = blockIdx.x * blockDim.x + threadIdx.x;
  if (i < N) { count[i] = 0u; count2[i] = 0u; }
}

__global__ void k_hist(const int* __restrict__ edge_index,
                       unsigned* __restrict__ count_dst,
                       unsigned* __restrict__ count_src, int E) {
  int e = blockIdx.x * blockDim.x + threadIdx.x;
  if (e < E) {
    atomicAdd(&count_dst[edge_index[(size_t)E + e]], 1u);
    atomicAdd(&count_src[edge_index[e]], 1u);
  }
}

__global__ __launch_bounds__(1024) void k_scan2(
    const unsigned* __restrict__ c0, unsigned* __restrict__ o0, unsigned* __restrict__ u0,
    const unsigned* __restrict__ c1, unsigned* __restrict__ o1, unsigned* __restrict__ u1,
    int N) {
  const unsigned* count = blockIdx.x ? c1 : c0;
  unsigned* offs   = blockIdx.x ? o1 : o0;
  unsigned* cursor = blockIdx.x ? u1 : u0;
  __shared__ unsigned buf[1024];
  __shared__ unsigned carry;
  if (threadIdx.x == 0) carry = 0u;
  __syncthreads();
  for (int base = 0; base < N; base += 1024) {
    int i = base + threadIdx.x;
    unsigned v = (i < N) ? count[i] : 0u;
    buf[threadIdx.x] = v;
    __syncthreads();
    for (int off = 1; off < 1024; off <<= 1) {
      unsigned t = (threadIdx.x >= (unsigned)off) ? buf[threadIdx.x - off] : 0u;
      __syncthreads();
      buf[threadIdx.x] += t;
      __syncthreads();
    }
    unsigned excl = buf[threadIdx.x] - v + carry;
    if (i < N) { offs[i] = excl; cursor[i] = excl; }
    __syncthreads();
    if (threadIdx.x == 1023) carry += buf[1023];
    __syncthreads();
  }
  if (threadIdx.x == 0) offs[N] = carry;
}

__global__ void k_scatter(const int* __restrict__ edge_index,
                          unsigned* __restrict__ cursor, unsigned* __restrict__ sorted,
                          unsigned* __restrict__ cursor2, unsigned* __restrict__ sorted2,
                          int E) {
  int e = blockIdx.x * blockDim.x + threadIdx.x;
  if (e < E) {
    unsigned p0 = atomicAdd(&cursor[edge_index[(size_t)E + e]], 1u);
    sorted[p0] = (unsigned)e;
    unsigned p1 = atomicAdd(&cursor2[edge_index[e]], 1u);
    sorted2[p1] = (unsigned)e;
  }
}

// ---------------- fold q-projection into key weights ----------------
__global__ __launch_bounds__(256) void k_wfold(
    const float* __restrict__ Wq0, const float* __restrict__ Wq1,
    const float* __restrict__ Wkv0, const float* __restrict__ Wkv1,
    unsigned* __restrict__ WATp, unsigned* __restrict__ WBTp) {
  int idx = blockIdx.x * 256 + threadIdx.x;
  if (idx < 32 * 384) {
    int k2 = idx / 384, o = idx % 384;
    int h = o / 48, j = o % 48;
    const float* wq0 = Wq0 + (size_t)(2 * k2) * 256 + h * 32;
    const float* wq1 = Wq0 + (size_t)(2 * k2 + 1) * 256 + h * 32;
    const float* wk  = Wkv0 + (size_t)j * 512 + h * 32;
    float s0 = 0.f, s1 = 0.f;
#pragma unroll
    for (int m = 0; m < 32; m++) { s0 += wq0[m] * wk[m]; s1 += wq1[m] * wk[m]; }
    s0 *= 0.125f * INV_SQRT48; s1 *= 0.125f * INV_SQRT48;
    WATp[idx] = bf16r(s0) | (bf16r(s1) << 16);
  }
  idx -= 32 * 384;
  if (idx >= 0 && idx < 16 * 512) {
    int u2 = idx / 512, o2 = idx % 512;
    int h = o2 / 64, u = o2 % 64;
    const float* wa = Wq1 + (size_t)(2 * u2) * 128 + h * 16;
    const float* wb = Wq1 + (size_t)(2 * u2 + 1) * 128 + h * 16;
    const float* wk = Wkv1 + (size_t)u * 256 + h * 16;
    float s0 = 0.f, s1 = 0.f;
#pragma unroll
    for (int t = 0; t < 16; t++) { s0 += wa[t] * wk[t]; s1 += wb[t] * wk[t]; }
    s0 *= 0.125f * INV_SQRT32; s1 *= 0.125f * INV_SQRT32;
    WBTp[idx] = bf16r(s0) | (bf16r(s1) << 16);
  }
}

// ---------------- node-side: norms + qk (folded) + s/d, 16 nodes/block --------
__global__ __launch_bounds__(256) void k_node(
    const float* __restrict__ node, const float* __restrict__ gamma0,
    const float* __restrict__ gamma1,
    const unsigned* __restrict__ WATp, const unsigned* __restrict__ WBTp,
    const float* __restrict__ Wsrc0, const float* __restrict__ Wsrc1,
    const float* __restrict__ Wdst0, const float* __restrict__ Wdst1,
    float* __restrict__ qkbuf, float* __restrict__ sbuf, float* __restrict__ dbuf,
    int N) {
  __shared__ unsigned WATL[32 * 384];
  __shared__ unsigned WBTL[16 * 512];
  __shared__ float    hL[16][160];
  __shared__ float    Wsd0L[64 * 64];
  __shared__ float    Wsd1L[32 * 32];

  int t = threadIdx.x;
  for (int i = t; i < 32 * 384; i += 256) WATL[i] = WATp[i];
  for (int i = t; i < 16 * 512; i += 256) WBTL[i] = WBTp[i];
  for (int i = t; i < 64 * 64; i += 256) {
    int k = i >> 6, o3 = i & 63, wh = o3 >> 5, j = o3 & 31;
    Wsd0L[i] = (wh ? Wdst0 : Wsrc0)[k * 32 + j];
  }
  for (int i = t; i < 32 * 32; i += 256) {
    int u = i >> 5, o4 = i & 31, wh = o4 >> 4, v = o4 & 15;
    Wsd1L[i] = (wh ? Wdst1 : Wsrc1)[u * 16 + v];
  }

  int wid = t >> 6, lane = t & 63;
  int n0 = blockIdx.x * 16;
  int nmax = min(16, N - n0);
  if (nmax <= 0) return;

  for (int nl = wid * 4; nl < min(wid * 4 + 4, nmax); nl++) {
    const float* nrow = node + (size_t)(n0 + nl) * 160;
    float v0 = nrow[lane];
    float mu = wsum64(v0) * (1.0f / 64.0f);
    float dv = v0 - mu;
    float var = wsum64(dv * dv) * (1.0f / 64.0f);
    float rs0 = rsqrtf(var + EPSV);
    float a = nrow[64 + lane];
    float b = (lane < 32) ? nrow[128 + lane] : 0.0f;
    float vn = wsum64(a * a + b * b) * (1.0f / 32.0f);
    float rs1 = rsqrtf(vn + EPSV);
    hL[nl][lane] = dv * rs0 * gamma0[lane];
    hL[nl][64 + lane] = a * rs1 * gamma1[lane / 3];
    if (lane < 32) hL[nl][128 + lane] = b * rs1 * gamma1[(64 + lane) / 3];
  }
  __syncthreads();

  int hh = lane & 7, rr = lane >> 3;
  int i0 = t >> 6;
  for (int s = 0; s < 8; s++) {
    int i = i0 + 4 * s;
    if (i >= 30) break;
    int J = rr * 30 + i;
    float acc[16];
#pragma unroll
    for (int n = 0; n < 16; n++) acc[n] = 0.f;
    if (J < 48) {
      int o = hh * 48 + J;
#pragma unroll 2
      for (int k2 = 0; k2 < 32; k2++) {
        unsigned pr = WATL[k2 * 384 + o];
        float w0 = __uint_as_float(pr << 16);
        float w1 = __uint_as_float(pr & 0xFFFF0000u);
#pragma unroll
        for (int n = 0; n < 16; n++) {
          float2 hp = *reinterpret_cast<const float2*>(&hL[n][2 * k2]);
          acc[n] += hp.x * w0 + hp.y * w1;
        }
      }
    } else {
      int u = (J - 48) / 3, c = (J - 48) - 3 * u;
      int o2 = hh * 64 + u;
#pragma unroll 2
      for (int u2 = 0; u2 < 16; u2++) {
        unsigned pr = WBTL[u2 * 512 + o2];
        float w0 = __uint_as_float(pr << 16);
        float w1 = __uint_as_float(pr & 0xFFFF0000u);
#pragma unroll
        for (int n = 0; n < 16; n++)
          acc[n] += hL[n][64 + (2 * u2) * 3 + c] * w0 +
                    hL[n][64 + (2 * u2 + 1) * 3 + c] * w1;
      }
    }
    for (int n = 0; n < nmax; n++)
      qkbuf[(size_t)(n0 + n) * 1920 + i * 64 + lane] = acc[n];
  }

  if (t < 64) {
    int wh = t >> 5, j = t & 31;
    float acc[16];
#pragma unroll
    for (int n = 0; n < 16; n++) acc[n] = 0.f;
    for (int k = 0; k < 64; k++) {
      float w = Wsd0L[k * 64 + t];
#pragma unroll
      for (int n = 0; n < 16; n++) acc[n] += hL[n][k] * w;
    }
    float* obuf = wh ? dbuf : sbuf;
    for (int n = 0; n < nmax; n++) obuf[(size_t)(n0 + n) * 80 + j] = acc[n] * 0.125f;
  } else if (t < 160) {
    int idx = t - 64;
    int wh = idx / 48, vc = idx % 48, v = vc / 3, c = vc - 3 * v;
    float acc[16];
#pragma unroll
    for (int n = 0; n < 16; n++) acc[n] = 0.f;
    for (int u = 0; u < 32; u++) {
      float w = Wsd1L[u * 32 + wh * 16 + v];
#pragma unroll
      for (int n = 0; n < 16; n++) acc[n] += hL[n][64 + u * 3 + c] * w;
    }
    float* obuf = wh ? dbuf : sbuf;
    for (int n = 0; n < nmax; n++)
      obuf[(size_t)(n0 + n) * 80 + 32 + vc] = acc[n] * INV_SQRT32;
  }
}

// ---- per-lane owner-computes cp: lane u owns cp0[u] (u<48) and cp1[u][0..2] ----
// x elements needed: u<32: x[u]; else x[32+3t+{0,1,2}], t = u<48 ? u-32 : u-48.
// W_rbf columns: colA = (u<48) ? u : 48+u (w000/w110/dup), colB = 48+u (w011/w101/w111).
__device__ __forceinline__ void cp_own_build(
    int u, float xa, float xb, float xc, float wA, float wB,
    float y0, float ya, float yb, float yc,
    float& cp0, float& c0, float& c1, float& c2) {
  if (u < 32) {
    float t0 = wA * xa; cp0 = t0 * y0;
    float t1 = wB * xa; c0 = t1 * ya; c1 = t1 * yb; c2 = t1 * yc;
  } else if (u < 48) {
    float dv = xa * ya + xb * yb + xc * yc;
    cp0 = wA * dv * INV_SQRT3;
    float t1 = wB * y0; c0 = t1 * xa; c1 = t1 * xb; c2 = t1 * xc;
  } else {
    cp0 = 0.f;
    float t1 = wB * INV_SQRT2;
    c0 = t1 * (xb * yc - xc * yb);
    c1 = t1 * (xc * ya - xa * yc);
    c2 = t1 * (xa * yb - xb * ya);
  }
}

// ---------------- src-major logit pass: fence-free register cp ----------------
__global__ __launch_bounds__(256) void k_logit(
    const float* __restrict__ rbf, const float* __restrict__ rsh,
    const int* __restrict__ edge_index,
    const float* __restrict__ W_rbf,
    const float* __restrict__ qkbuf, const float* __restrict__ sbuf,
    const float* __restrict__ dbuf,
    const unsigned* __restrict__ offs2, const unsigned* __restrict__ sorted2,
    float* __restrict__ logits, int N, int E) {
  int tid = threadIdx.x, wid = tid >> 6, lane = tid & 63;
  int u = lane;
  bool cls0 = (u < 32);
  int tx = cls0 ? 0 : ((u < 48) ? u - 32 : u - 48);
  int idxA = cls0 ? u : 32 + 3 * tx;
  int idxB = cls0 ? u : idxA + 1;
  int idxC = cls0 ? u : idxA + 2;
  int colA = (u < 48) ? u : 48 + u;
  int colB = 48 + u;
  float wcA[16], wcB[16];
#pragma unroll
  for (int k = 0; k < 16; k++) {
    wcA[k] = W_rbf[k * 112 + colA];
    wcB[k] = W_rbf[k * 112 + colB];
  }
  int J1 = 48 + 3 * u, J2 = J1 + 1, J3 = J1 + 2;
  int o0 = (u < 48) ? ((u % 30) * 64 + (u / 30) * 8) : 0;
  int o1 = (J1 % 30) * 64 + (J1 / 30) * 8;
  int o2 = (J2 % 30) * 64 + (J2 / 30) * 8;
  int o3 = (J3 % 30) * 64 + (J3 / 30) * 8;

  int n = blockIdx.x * 4 + wid;
  if (n >= N) return;
  unsigned off = offs2[n];
  int deg = (int)(offs2[n + 1] - off);
  if (deg == 0) return;

  // gather qk_own[q][h] once per node
  const float* qkr = qkbuf + (size_t)n * 1920;
  float qk0[8], qk1[8], qk2[8], qk3[8];
  if (u < 48) {
    float4 a = *(const float4*)(qkr + o0);
    float4 b = *(const float4*)(qkr + o0 + 4);
    qk0[0]=a.x; qk0[1]=a.y; qk0[2]=a.z; qk0[3]=a.w;
    qk0[4]=b.x; qk0[5]=b.y; qk0[6]=b.z; qk0[7]=b.w;
  } else {
#pragma unroll
    for (int h = 0; h < 8; h++) qk0[h] = 0.f;
  }
  {
    float4 a = *(const float4*)(qkr + o1);
    float4 b = *(const float4*)(qkr + o1 + 4);
    qk1[0]=a.x; qk1[1]=a.y; qk1[2]=a.z; qk1[3]=a.w;
    qk1[4]=b.x; qk1[5]=b.y; qk1[6]=b.z; qk1[7]=b.w;
  }
  {
    float4 a = *(const float4*)(qkr + o2);
    float4 b = *(const float4*)(qkr + o2 + 4);
    qk2[0]=a.x; qk2[1]=a.y; qk2[2]=a.z; qk2[3]=a.w;
    qk2[4]=b.x; qk2[5]=b.y; qk2[6]=b.z; qk2[7]=b.w;
  }
  {
    float4 a = *(const float4*)(qkr + o3);
    float4 b = *(const float4*)(qkr + o3 + 4);
    qk3[0]=a.x; qk3[1]=a.y; qk3[2]=a.z; qk3[3]=a.w;
    qk3[4]=b.x; qk3[5]=b.y; qk3[6]=b.z; qk3[7]=b.w;
  }
  float s0 = sbuf[(size_t)n * 80 + idxA];
  float s1 = sbuf[(size_t)n * 80 + idxB];
  float s2 = sbuf[(size_t)n * 80 + idxC];

  int b0 = lane & 1, b1 = (lane >> 1) & 1, b2 = (lane >> 2) & 1;

  for (int t = 0; t < deg; t++) {
    unsigned e = sorted2[off + t];
    int dst = edge_index[(size_t)E + e];
    const float* drow = dbuf + (size_t)dst * 80;
    float xa = s0 + drow[idxA];
    float xb = s1 + drow[idxB];
    float xc = s2 + drow[idxC];
    const float* rr = rbf + (size_t)e * 16;
    float4 r0 = *(const float4*)(rr);
    float4 r1 = *(const float4*)(rr + 4);
    float4 r2 = *(const float4*)(rr + 8);
    float4 r3 = *(const float4*)(rr + 12);
    float4 y  = *(const float4*)(rsh + (size_t)e * 4);
    float wA = r0.x*wcA[0]+r0.y*wcA[1]+r0.z*wcA[2]+r0.w*wcA[3]
             + r1.x*wcA[4]+r1.y*wcA[5]+r1.z*wcA[6]+r1.w*wcA[7]
             + r2.x*wcA[8]+r2.y*wcA[9]+r2.z*wcA[10]+r2.w*wcA[11]
             + r3.x*wcA[12]+r3.y*wcA[13]+r3.z*wcA[14]+r3.w*wcA[15];
    float wB = r0.x*wcB[0]+r0.y*wcB[1]+r0.z*wcB[2]+r0.w*wcB[3]
             + r1.x*wcB[4]+r1.y*wcB[5]+r1.z*wcB[6]+r1.w*wcB[7]
             + r2.x*wcB[8]+r2.y*wcB[9]+r2.z*wcB[10]+r2.w*wcB[11]
             + r3.x*wcB[12]+r3.y*wcB[13]+r3.z*wcB[14]+r3.w*wcB[15];
    float cp0, c0, c1, c2;
    cp_own_build(u, xa, xb, xc, wA, wB, y.x, y.y, y.z, y.w, cp0, c0, c1, c2);

    // per-head partials then butterfly head-fold
    float p[8];
#pragma unroll
    for (int h = 0; h < 8; h++)
      p[h] = qk0[h]*cp0 + qk1[h]*c0 + qk2[h]*c1 + qk3[h]*c2;
    float q4[4];
#pragma unroll
    for (int i = 0; i < 4; i++) {
      float mine = b0 ? p[2*i+1] : p[2*i];
      float send = b0 ? p[2*i]   : p[2*i+1];
      q4[i] = mine + __shfl_xor(send, 1);
    }
    float q2a, q2b;
    {
      float mine = b1 ? q4[1] : q4[0];
      float send = b1 ? q4[0] : q4[1];
      q2a = mine + __shfl_xor(send, 2);
      mine = b1 ? q4[3] : q4[2];
      send = b1 ? q4[2] : q4[3];
      q2b = mine + __shfl_xor(send, 2);
    }
    float mine = b2 ? q2b : q2a;
    float send = b2 ? q2a : q2b;
    float q1 = mine + __shfl_xor(send, 4);
    q1 += __shfl_xor(q1, 8);
    q1 += __shfl_xor(q1, 16);
    q1 += __shfl_xor(q1, 32);
    if (lane < 8) logits[(size_t)e * 8 + lane] = q1 * SCALE_ATT;
  }
}

// ---------------- per-(node,head) segment max ----------------
__global__ __launch_bounds__(256) void k_max(
    const float* __restrict__ logits,
    const unsigned* __restrict__ offs, const unsigned* __restrict__ sorted,
    float* __restrict__ mxbuf, int N) {
  int tid = threadIdx.x, wid = tid >> 6, lane = tid & 63;
  int n = blockIdx.x * 4 + wid;
  if (n >= N) return;
  unsigned off = offs[n];
  int deg = (int)(offs[n + 1] - off);
  float mx = -3.4e38f;
  for (int i = lane; i < deg * 8; i += 64) {
    unsigned e = sorted[off + (i >> 3)];
    mx = fmaxf(mx, logits[(size_t)e * 8 + (i & 7)]);
  }
  mx = fmaxf(mx, __shfl_xor(mx, 8));
  mx = fmaxf(mx, __shfl_xor(mx, 16));
  mx = fmaxf(mx, __shfl_xor(mx, 32));
  if (lane < 8) mxbuf[(size_t)n * 8 + lane] = mx;
}

// ---------------- dst-major aggregation: fence-free, two-pass softmax ----------
__global__ __launch_bounds__(256, 4) void k_agg(
    const float* __restrict__ rbf, const float* __restrict__ rsh,
    const int* __restrict__ edge_index,
    const float* __restrict__ W_rbf, const float* __restrict__ Wkv0,
    const float* __restrict__ Wkv1,
    const float* __restrict__ sbuf, const float* __restrict__ dbuf,
    const float* __restrict__ logits, const float* __restrict__ mxbuf,
    const unsigned* __restrict__ offs, const unsigned* __restrict__ sorted,
    float* __restrict__ mlbuf, int N, int E) {
  __shared__ float S[4 * 1952];
  int tid = threadIdx.x, wid = tid >> 6, lane = tid & 63;
  float* acpL = S + wid * 1952;
  int u = lane;
  bool cls0 = (u < 32);
  int tx = cls0 ? 0 : ((u < 48) ? u - 32 : u - 48);
  int idxA = cls0 ? u : 32 + 3 * tx;
  int idxB = cls0 ? u : idxA + 1;
  int idxC = cls0 ? u : idxA + 2;
  int colA = (u < 48) ? u : 48 + u;
  int colB = 48 + u;
  float wcA[16], wcB[16];
#pragma unroll
  for (int k = 0; k < 16; k++) {
    wcA[k] = W_rbf[k * 112 + colA];
    wcB[k] = W_rbf[k * 112 + colB];
  }

  int n = blockIdx.x * 4 + wid;
  if (n >= N) return;
  unsigned off = offs[n];
  int deg = (int)(offs[n + 1] - off);
  float* mlrow = mlbuf + (size_t)n * 640;
  if (deg == 0) {
#pragma unroll
    for (int g = 0; g < 10; g++) mlrow[g * 64 + lane] = 0.f;
    return;
  }

  float d0 = dbuf[(size_t)n * 80 + idxA];
  float d1 = dbuf[(size_t)n * 80 + idxB];
  float d2 = dbuf[(size_t)n * 80 + idxC];
  float4 mxa = *(const float4*)(mxbuf + (size_t)n * 8);
  float4 mxb = *(const float4*)(mxbuf + (size_t)n * 8 + 4);

  float acc0[8], acc1[8], acc2[8], acc3[8];
#pragma unroll
  for (int h = 0; h < 8; h++) { acc0[h]=0.f; acc1[h]=0.f; acc2[h]=0.f; acc3[h]=0.f; }
  float z_own = 0.f;

  for (int t = 0; t < deg; t++) {
    unsigned e = sorted[off + t];
    int src = edge_index[e];
    const float* srow = sbuf + (size_t)src * 80;
    float xa = srow[idxA] + d0;
    float xb = srow[idxB] + d1;
    float xc = srow[idxC] + d2;
    const float* rr = rbf + (size_t)e * 16;
    float4 r0 = *(const float4*)(rr);
    float4 r1 = *(const float4*)(rr + 4);
    float4 r2 = *(const float4*)(rr + 8);
    float4 r3 = *(const float4*)(rr + 12);
    float4 y  = *(const float4*)(rsh + (size_t)e * 4);
    float wA = r0.x*wcA[0]+r0.y*wcA[1]+r0.z*wcA[2]+r0.w*wcA[3]
             + r1.x*wcA[4]+r1.y*wcA[5]+r1.z*wcA[6]+r1.w*wcA[7]
             + r2.x*wcA[8]+r2.y*wcA[9]+r2.z*wcA[10]+r2.w*wcA[11]
             + r3.x*wcA[12]+r3.y*wcA[13]+r3.z*wcA[14]+r3.w*wcA[15];
    float wB = r0.x*wcB[0]+r0.y*wcB[1]+r0.z*wcB[2]+r0.w*wcB[3]
             + r1.x*wcB[4]+r1.y*wcB[5]+r1.z*wcB[6]+r1.w*wcB[7]
             + r2.x*wcB[8]+r2.y*wcB[9]+r2.z*wcB[10]+r2.w*wcB[11]
             + r3.x*wcB[12]+r3.y*wcB[13]+r3.z*wcB[14]+r3.w*wcB[15];
    float cp0, c0, c1, c2;
    cp_own_build(u, xa, xb, xc, wA, wB, y.x, y.y, y.z, y.w, cp0, c0, c1, c2);

    float4 lgA = *(const float4*)(logits + (size_t)e * 8);
    float4 lgB = *(const float4*)(logits + (size_t)e * 8 + 4);
    float aa[8];
    aa[0] = __expf(lgA.x - mxa.x); aa[1] = __expf(lgA.y - mxa.y);
    aa[2] = __expf(lgA.z - mxa.z); aa[3] = __expf(lgA.w - mxa.w);
    aa[4] = __expf(lgB.x - mxb.x); aa[5] = __expf(lgB.y - mxb.y);
    aa[6] = __expf(lgB.z - mxb.z); aa[7] = __expf(lgB.w - mxb.w);
    float aaz = (u & 4) ? ((u & 2) ? ((u & 1) ? aa[7] : aa[6])
                                   : ((u & 1) ? aa[5] : aa[4]))
                        : ((u & 2) ? ((u & 1) ? aa[3] : aa[2])
                                   : ((u & 1) ? aa[1] : aa[0]));
    z_own += aaz;
#pragma unroll
    for (int h = 0; h < 8; h++) {
      acc0[h] += aa[h] * cp0;
      acc1[h] += aa[h] * c0;
      acc2[h] += aa[h] * c1;
      acc3[h] += aa[h] * c2;
    }
  }

  // stage acp: J0 = u (u<48), J1..3 = 48+3u+c
  int base = 48 + 3 * u;
#pragma unroll
  for (int h = 0; h < 8; h++) {
    if (u < 48) acpL[h * 241 + u] = acc0[h];
    acpL[h * 241 + base + 0] = acc1[h];
    acpL[h * 241 + base + 1] = acc2[h];
    acpL[h * 241 + base + 2] = acc3[h];
  }
  LDS_FENCE();

  // value GEMM + normalize (z_own on lane l = z[l&7])
#pragma unroll
  for (int g = 0; g < 4; g++) {
    int col = g * 64 + lane;       // h*32+m
    int h2 = col >> 5;
    float a2 = 0.f;
#pragma unroll
    for (int k = 0; k < 48; k++) a2 += acpL[h2 * 241 + k] * Wkv0[k * 512 + 256 + col];
    float zz = __shfl(z_own, h2);
    mlrow[col] = a2 * INV_SQRT48 / (zz + 1e-16f);
  }
#pragma unroll
  for (int g = 0; g < 6; g++) {
    int pc = g * 64 + lane;        // p*3+c, p = h*16+u
    int p = pc / 3, c = pc - p * 3;
    int h2 = p >> 4;
    float a2 = 0.f;
#pragma unroll
    for (int w = 0; w < 64; w++)
      a2 += acpL[h2 * 241 + 48 + w * 3 + c] * Wkv1[w * 256 + 128 + p];
    float zz = __shfl(z_own, h2);
    mlrow[256 + pc] = a2 * 0.125f / (zz + 1e-16f);
  }
}

// ---------------- output projection + residual ----------------
__global__ __launch_bounds__(256) void k_out(
    const float* __restrict__ node, const float* __restrict__ mlbuf,
    const float* __restrict__ Wmsg0, const float* __restrict__ Wmsg1,
    float* __restrict__ out, int N) {
  __shared__ float mlw[4][640];
  int tid = threadIdx.x, wid = tid >> 6, lane = tid & 63;
  int n = blockIdx.x * 4 + wid;
  if (n >= N) return;
  const float* mlrow = mlbuf + (size_t)n * 640;
#pragma unroll
  for (int g = 0; g < 10; g++) mlw[wid][g * 64 + lane] = mlrow[g * 64 + lane];
  LDS_FENCE();
  const float* nrow = node + (size_t)n * 160;
  float* orow = out + (size_t)n * 160;
  {
    float a2 = 0.f;
#pragma unroll 8
    for (int j = 0; j < 256; j++) a2 += mlw[wid][j] * Wmsg0[j * 64 + lane];
    orow[lane] = nrow[lane] + a2 * 0.0625f;
  }
#pragma unroll
  for (int i0 = 0; i0 < 96; i0 += 64) {
    int i = i0 + lane;
    if (i < 96) {
      int v = i / 3, c = i - v * 3;
      float a2 = 0.f;
#pragma unroll 8
      for (int p = 0; p < 128; p++) a2 += mlw[wid][256 + p * 3 + c] * Wmsg1[p * 32 + v];
      orow[64 + i] = nrow[64 + i] + a2 * INV_SQRT128;
    }
  }
}

extern "C" void kernel_launch(void* const* d_in, const int* in_sizes, int n_in,
                              void* d_out, int out_size, void* d_ws, size_t ws_size,
                              hipStream_t stream) {
  (void)n_in; (void)out_size; (void)ws_size;
  const float* node   = (const float*)d_in[0];
  const float* rbf    = (const float*)d_in[1];
  const float* rsh    = (const float*)d_in[2];
  const int*   eidx   = (const int*)d_in[3];
  const float* gamma0 = (const float*)d_in[4];
  const float* gamma1 = (const float*)d_in[5];
  const float* Wq0    = (const float*)d_in[6];
  const float* Wq1    = (const float*)d_in[7];
  const float* Wsrc0  = (const float*)d_in[8];
  const float* Wsrc1  = (const float*)d_in[9];
  const float* Wdst0  = (const float*)d_in[10];
  const float* Wdst1  = (const float*)d_in[11];
  const float* W_rbf  = (const float*)d_in[12];
  const float* Wkv0   = (const float*)d_in[13];
  const float* Wkv1   = (const float*)d_in[14];
  const float* Wmsg0  = (const float*)d_in[15];
  const float* Wmsg1  = (const float*)d_in[16];
  float* out = (float*)d_out;

  int N = in_sizes[0] / 160;
  int E = in_sizes[3] / 2;

  unsigned* WATp = (unsigned*)d_ws;                       // 32*384
  unsigned* WBTp = WATp + 32 * 384;                       // 16*512
  float* sbuf   = (float*)(WBTp + 16 * 512);              // N*80
  float* dbuf   = sbuf + (size_t)N * 80;                  // N*80
  float* qkbuf  = dbuf + (size_t)N * 80;                  // N*1920
  float* mlbuf  = qkbuf + (size_t)N * 1920;               // N*640
  float* logits = mlbuf + (size_t)N * 640;                // E*8
  float* mxbuf  = logits + (size_t)E * 8;                 // N*8
  unsigned* count   = (unsigned*)(mxbuf + (size_t)N * 8);   // N
  unsigned* offs    = count + N;                            // N+1
  unsigned* cursor  = offs + N + 1;                         // N
  unsigned* sorted  = cursor + N;                           // E
  unsigned* count2  = sorted + E;                           // N
  unsigned* offs2   = count2 + N;                           // N+1
  unsigned* cursor2 = offs2 + N + 1;                        // N
  unsigned* sorted2 = cursor2 + N;                          // E

  hipLaunchKernelGGL(init_count, dim3((N + 255) / 256), dim3(256), 0, stream,
                     count, count2, N);
  hipLaunchKernelGGL(k_hist, dim3((E + 255) / 256), dim3(256), 0, stream,
                     eidx, count, count2, E);
  hipLaunchKernelGGL(k_scan2, dim3(2), dim3(1024), 0, stream,
                     count, offs, cursor, count2, offs2, cursor2, N);
  hipLaunchKernelGGL(k_scatter, dim3((E + 255) / 256), dim3(256), 0, stream,
                     eidx, cursor, sorted, cursor2, sorted2, E);
  hipLaunchKernelGGL(k_wfold, dim3(80), dim3(256), 0, stream,
                     Wq0, Wq1, Wkv0, Wkv1, WATp, WBTp);
  hipLaunchKernelGGL(k_node, dim3((N + 15) / 16), dim3(256), 0, stream,
                     node, gamma0, gamma1, WATp, WBTp, Wsrc0, Wsrc1, Wdst0, Wdst1,
                     qkbuf, sbuf, dbuf, N);
  hipLaunchKernelGGL(k_logit, dim3((N + 3) / 4), dim3(256), 0, stream,
                     rbf, rsh, eidx, W_rbf, qkbuf, sbuf, dbuf,
                     offs2, sorted2, logits, N, E);
  hipLaunchKernelGGL(k_max, dim3((N + 3) / 4), dim3(256), 0, stream,
                     logits, offs, sorted, mxbuf, N);
  hipLaunchKernelGGL(k_agg, dim3((N + 3) / 4), dim3(256), 0, stream,
                     rbf, rsh, eidx, W_rbf, Wkv0, Wkv1, sbuf, dbuf, logits, mxbuf,
                     offs, sorted, mlbuf, N, E);
  hipLaunchKernelGGL(k_out, dim3((N + 3) / 4), dim3(256), 0, stream,
                     node, mlbuf, Wmsg0, Wmsg1, out, N);
}

// Round 8
// 602.226 us; speedup vs baseline: 1.4544x; 1.2198x over previous
//
#include <hip/hip_runtime.h>
#include <math.h>

// TransPhormer equivariant graph attention — round 8.
// vs r7: k_node (280us, 1 wave/SIMD, LDS-bound) replaced by:
//   k_norm: norms + s/d proj (global weights, L1-resident), writes hbuf
//   k_qk:   folded-qk GEMM, wave-specialized (wid0=scalar K=64; wid1..3=vector
//           c=wid-1 wave-uniform), register tile 6-8 out x 8 nodes, LDS 5KB,
//           broadcast-only LDS reads, coalesced weight tables WS/WV.
// qkbuf layout CHANGED to [n][J][h] (J<240, h<8): scalar J<48 at J*8+h;
//   vector (u,c) at (48+3u+c)*8+h = 384+24u+8c+h. k_logit offsets updated.
// cp layout (240): [0,48) = cp0 ; 48 + u*3 + c = cp1[u][c]

constexpr float EPSV        = 1e-5f;
constexpr float INV_SQRT3   = 0.5773502691896258f;
constexpr float INV_SQRT2   = 0.7071067811865476f;
constexpr float INV_SQRT32  = 0.17677669529663687f;
constexpr float INV_SQRT48  = 0.14433756729740643f;
constexpr float INV_SQRT128 = 0.08838834764831845f;
constexpr float SCALE_ATT   = 0.14433756729740643f; // 1/sqrt(48)

#define LDS_FENCE() do { asm volatile("s_waitcnt lgkmcnt(0)" ::: "memory"); \
                         __builtin_amdgcn_sched_barrier(0); } while (0)

__device__ __forceinline__ float wsum64(float v) {
#pragma unroll
  for (int m = 1; m < 64; m <<= 1) v += __shfl_xor(v, m);
  return v;
}

__device__ __forceinline__ unsigned bf16r(float f) {
  unsigned b = __float_as_uint(f);
  return (b + 0x7FFFu + ((b >> 16) & 1u)) >> 16;
}

// ---------------- sort machinery (dst-sort AND src-sort) ----------------
__global__ void init_count(unsigned* __restrict__ count, unsigned* __restrict__ count2,
                           int N) {
  int i = blockIdx.x * blockDim.x + threadIdx.x;
  if (i < N) { count[i] = 0u; count2[i] = 0u; }
}

__global__ void k_hist(const int* __restrict__ edge_index,
                       unsigned* __restrict__ count_dst,
                       unsigned* __restrict__ count_src, int E) {
  int e = blockIdx.x * blockDim.x + threadIdx.x;
  if (e < E) {
    atomicAdd(&count_dst[edge_index[(size_t)E + e]], 1u);
    atomicAdd(&count_src[edge_index[e]], 1u);
  }
}

__global__ __launch_bounds__(1024) void k_scan2(
    const unsigned* __restrict__ c0, unsigned* __restrict__ o0, unsigned* __restrict__ u0,
    const unsigned* __restrict__ c1, unsigned* __restrict__ o1, unsigned* __restrict__ u1,
    int N) {
  const unsigned* count = blockIdx.x ? c1 : c0;
  unsigned* offs   = blockIdx.x ? o1 : o0;
  unsigned* cursor = blockIdx.x ? u1 : u0;
  __shared__ unsigned buf[1024];
  __shared__ unsigned carry;
  if (threadIdx.x == 0) carry = 0u;
  __syncthreads();
  for (int base = 0; base < N; base += 1024) {
    int i = base + threadIdx.x;
    unsigned v = (i < N) ? count[i] : 0u;
    buf[threadIdx.x] = v;
    __syncthreads();
    for (int off = 1; off < 1024; off <<= 1) {
      unsigned t = (threadIdx.x >= (unsigned)off) ? buf[threadIdx.x - off] : 0u;
      __syncthreads();
      buf[threadIdx.x] += t;
      __syncthreads();
    }
    unsigned excl = buf[threadIdx.x] - v + carry;
    if (i < N) { offs[i] = excl; cursor[i] = excl; }
    __syncthreads();
    if (threadIdx.x == 1023) carry += buf[1023];
    __syncthreads();
  }
  if (threadIdx.x == 0) offs[N] = carry;
}

__global__ void k_scatter(const int* __restrict__ edge_index,
                          unsigned* __restrict__ cursor, unsigned* __restrict__ sorted,
                          unsigned* __restrict__ cursor2, unsigned* __restrict__ sorted2,
                          int E) {
  int e = blockIdx.x * blockDim.x + threadIdx.x;
  if (e < E) {
    unsigned p0 = atomicAdd(&cursor[edge_index[(size_t)E + e]], 1u);
    sorted[p0] = (unsigned)e;
    unsigned p1 = atomicAdd(&cursor2[edge_index[e]], 1u);
    sorted2[p1] = (unsigned)e;
  }
}

// ------- fold q-projection into key weights, output-major coalesced tables ----
// WS[k2*384 + J*8 + h]: bf16x2 over k={2k2,2k2+1}, scalar (J<48)
// WV[u2*512 + u*8 + h]: bf16x2 over u'={2u2,2u2+1}, vector (c-independent)
__global__ __launch_bounds__(256) void k_wfold2(
    const float* __restrict__ Wq0, const float* __restrict__ Wq1,
    const float* __restrict__ Wkv0, const float* __restrict__ Wkv1,
    unsigned* __restrict__ WS, unsigned* __restrict__ WV) {
  int idx = blockIdx.x * 256 + threadIdx.x;
  if (idx < 32 * 384) {
    int k2 = idx / 384, oq = idx % 384;
    int J = oq >> 3, h = oq & 7;
    const float* wq0 = Wq0 + (size_t)(2 * k2) * 256 + h * 32;
    const float* wq1 = Wq0 + (size_t)(2 * k2 + 1) * 256 + h * 32;
    const float* wk  = Wkv0 + (size_t)J * 512 + h * 32;
    float s0 = 0.f, s1 = 0.f;
#pragma unroll
    for (int m = 0; m < 32; m++) { s0 += wq0[m] * wk[m]; s1 += wq1[m] * wk[m]; }
    s0 *= 0.125f * INV_SQRT48; s1 *= 0.125f * INV_SQRT48;
    WS[idx] = bf16r(s0) | (bf16r(s1) << 16);
  }
  idx -= 32 * 384;
  if (idx >= 0 && idx < 16 * 512) {
    int u2 = idx / 512, uh = idx % 512;
    int u = uh >> 3, h = uh & 7;
    const float* wa = Wq1 + (size_t)(2 * u2) * 128 + h * 16;
    const float* wb = Wq1 + (size_t)(2 * u2 + 1) * 128 + h * 16;
    const float* wk = Wkv1 + (size_t)u * 256 + h * 16;
    float s0 = 0.f, s1 = 0.f;
#pragma unroll
    for (int t = 0; t < 16; t++) { s0 += wa[t] * wk[t]; s1 += wb[t] * wk[t]; }
    s0 *= 0.125f * INV_SQRT32; s1 *= 0.125f * INV_SQRT32;
    WV[idx] = bf16r(s0) | (bf16r(s1) << 16);
  }
}

// ---------------- norms + s/d projections; h -> hbuf ----------------
__global__ __launch_bounds__(256) void k_norm(
    const float* __restrict__ node, const float* __restrict__ gamma0,
    const float* __restrict__ gamma1,
    const float* __restrict__ Wsrc0, const float* __restrict__ Wsrc1,
    const float* __restrict__ Wdst0, const float* __restrict__ Wdst1,
    float* __restrict__ hbuf, float* __restrict__ sbuf, float* __restrict__ dbuf,
    int N) {
  __shared__ float hL[4][160];
  int tid = threadIdx.x, wid = tid >> 6, lane = tid & 63;
  int n = blockIdx.x * 4 + wid;
  if (n >= N) return;
  float* h = hL[wid];
  const float* nrow = node + (size_t)n * 160;

  float v0 = nrow[lane];
  float mu = wsum64(v0) * (1.0f / 64.0f);
  float dv = v0 - mu;
  float var = wsum64(dv * dv) * (1.0f / 64.0f);
  float rs0 = rsqrtf(var + EPSV);
  float a = nrow[64 + lane];
  float b = (lane < 32) ? nrow[128 + lane] : 0.0f;
  float vn = wsum64(a * a + b * b) * (1.0f / 32.0f);
  float rs1 = rsqrtf(vn + EPSV);
  h[lane] = dv * rs0 * gamma0[lane];
  h[64 + lane] = a * rs1 * gamma1[lane / 3];
  if (lane < 32) h[128 + lane] = b * rs1 * gamma1[(64 + lane) / 3];
  LDS_FENCE();

  // write h
  float* hrow = hbuf + (size_t)n * 160;
  hrow[lane] = h[lane];
  hrow[64 + lane] = h[64 + lane];
  if (lane < 32) hrow[128 + lane] = h[128 + lane];

  // s/d scalar (64 outputs: wh*32+j)
  {
    int wh = lane >> 5, j = lane & 31;
    const float* W0 = wh ? Wdst0 : Wsrc0;
    float acc = 0.f;
#pragma unroll
    for (int k = 0; k < 64; k++) acc += h[k] * W0[k * 32 + j];
    (wh ? dbuf : sbuf)[(size_t)n * 80 + j] = acc * 0.125f;
  }
  // s/d vector (96 outputs)
#pragma unroll
  for (int i0 = 0; i0 < 96; i0 += 64) {
    int i = i0 + lane;
    if (i < 96) {
      int wh = i / 48, vc = i % 48, v = vc / 3, cc = vc - 3 * v;
      const float* W1 = wh ? Wdst1 : Wsrc1;
      float acc = 0.f;
#pragma unroll
      for (int u = 0; u < 32; u++) acc += h[64 + u * 3 + cc] * W1[u * 16 + v];
      (wh ? dbuf : sbuf)[(size_t)n * 80 + 32 + vc] = acc * INV_SQRT32;
    }
  }
}

// ---------------- folded-qk GEMM: 8 nodes/block, wave-specialized ----------------
// wid 0: scalar outputs oq=J*8+h (384), 6 g-slices; K = 32 bf16-pairs.
// wid 1..3: vector, c = wid-1; outputs uh=u*8+h (512), 8 g-slices; K = 16 pairs.
__global__ __launch_bounds__(256) void k_qk(
    const float* __restrict__ hbuf,
    const unsigned* __restrict__ WS, const unsigned* __restrict__ WV,
    float* __restrict__ qkbuf, int N) {
  __shared__ float hsL[8 * 64];       // h0 pairs: [n*64 + k]
  __shared__ float hoV[8 * 96];       // [n*96 + u2*6 + c*2 + j] = h1[2u2+j][c]
  int tid = threadIdx.x, wid = tid >> 6, lane = tid & 63;
  int n0 = blockIdx.x * 8;
  int nn = min(8, N - n0);
  if (nn <= 0) return;

  for (int idx = tid; idx < 512; idx += 256) {
    int n = idx >> 6, k = idx & 63;
    hsL[idx] = (n < nn) ? hbuf[(size_t)(n0 + n) * 160 + k] : 0.f;
  }
  for (int idx = tid; idx < 768; idx += 256) {
    int n = idx / 96, r = idx % 96, u2 = r / 6, q = r % 6, c = q >> 1, j = q & 1;
    hoV[idx] = (n < nn) ? hbuf[(size_t)(n0 + n) * 160 + 64 + (2 * u2 + j) * 3 + c] : 0.f;
  }
  __syncthreads();

  if (wid == 0) {
    float acc[6][8];
#pragma unroll
    for (int g = 0; g < 6; g++)
#pragma unroll
      for (int n = 0; n < 8; n++) acc[g][n] = 0.f;
    for (int k2 = 0; k2 < 32; ++k2) {
      float2 hp[8];
#pragma unroll
      for (int n = 0; n < 8; n++)
        hp[n] = *reinterpret_cast<const float2*>(&hsL[n * 64 + 2 * k2]);
#pragma unroll
      for (int g = 0; g < 6; g++) {
        unsigned pr = WS[k2 * 384 + g * 64 + lane];
        float w0 = __uint_as_float(pr << 16);
        float w1 = __uint_as_float(pr & 0xFFFF0000u);
#pragma unroll
        for (int n = 0; n < 8; n++) acc[g][n] += hp[n].x * w0 + hp[n].y * w1;
      }
    }
#pragma unroll
    for (int g = 0; g < 6; g++)
      for (int n = 0; n < nn; n++)
        qkbuf[(size_t)(n0 + n) * 1920 + g * 64 + lane] = acc[g][n];
  } else {
    int c = wid - 1;
    float acc[8][8];
#pragma unroll
    for (int g = 0; g < 8; g++)
#pragma unroll
      for (int n = 0; n < 8; n++) acc[g][n] = 0.f;
    for (int u2 = 0; u2 < 16; ++u2) {
      float2 hv[8];
#pragma unroll
      for (int n = 0; n < 8; n++)
        hv[n] = *reinterpret_cast<const float2*>(&hoV[n * 96 + u2 * 6 + 2 * c]);
#pragma unroll
      for (int g = 0; g < 8; g++) {
        unsigned pr = WV[u2 * 512 + g * 64 + lane];
        float w0 = __uint_as_float(pr << 16);
        float w1 = __uint_as_float(pr & 0xFFFF0000u);
#pragma unroll
        for (int n = 0; n < 8; n++) acc[g][n] += hv[n].x * w0 + hv[n].y * w1;
      }
    }
    int u = 0, h = lane & 7;
#pragma unroll
    for (int g = 0; g < 8; g++) {
      int uh = g * 64 + lane;
      u = uh >> 3;
      int p = 384 + u * 24 + c * 8 + h;
      for (int n = 0; n < nn; n++)
        qkbuf[(size_t)(n0 + n) * 1920 + p] = acc[g][n];
    }
  }
}

// ---- per-lane owner-computes cp: lane u owns cp0[u] (u<48) and cp1[u][0..2] ----
__device__ __forceinline__ void cp_own_build(
    int u, float xa, float xb, float xc, float wA, float wB,
    float y0, float ya, float yb, float yc,
    float& cp0, float& c0, float& c1, float& c2) {
  if (u < 32) {
    float t0 = wA * xa; cp0 = t0 * y0;
    float t1 = wB * xa; c0 = t1 * ya; c1 = t1 * yb; c2 = t1 * yc;
  } else if (u < 48) {
    float dv = xa * ya + xb * yb + xc * yc;
    cp0 = wA * dv * INV_SQRT3;
    float t1 = wB * y0; c0 = t1 * xa; c1 = t1 * xb; c2 = t1 * xc;
  } else {
    cp0 = 0.f;
    float t1 = wB * INV_SQRT2;
    c0 = t1 * (xb * yc - xc * yb);
    c1 = t1 * (xc * ya - xa * yc);
    c2 = t1 * (xa * yb - xb * ya);
  }
}

// ---------------- src-major logit pass: fence-free register cp ----------------
__global__ __launch_bounds__(256) void k_logit(
    const float* __restrict__ rbf, const float* __restrict__ rsh,
    const int* __restrict__ edge_index,
    const float* __restrict__ W_rbf,
    const float* __restrict__ qkbuf, const float* __restrict__ sbuf,
    const float* __restrict__ dbuf,
    const unsigned* __restrict__ offs2, const unsigned* __restrict__ sorted2,
    float* __restrict__ logits, int N, int E) {
  int tid = threadIdx.x, wid = tid >> 6, lane = tid & 63;
  int u = lane;
  bool cls0 = (u < 32);
  int tx = cls0 ? 0 : ((u < 48) ? u - 32 : u - 48);
  int idxA = cls0 ? u : 32 + 3 * tx;
  int idxB = cls0 ? u : idxA + 1;
  int idxC = cls0 ? u : idxA + 2;
  int colA = (u < 48) ? u : 48 + u;
  int colB = 48 + u;
  float wcA[16], wcB[16];
#pragma unroll
  for (int k = 0; k < 16; k++) {
    wcA[k] = W_rbf[k * 112 + colA];
    wcB[k] = W_rbf[k * 112 + colB];
  }
  // NEW layout: J at J*8+h
  int o0 = (u < 48) ? (u * 8) : 0;
  int o1 = 384 + u * 24;
  int o2 = o1 + 8;
  int o3 = o1 + 16;

  int n = blockIdx.x * 4 + wid;
  if (n >= N) return;
  unsigned off = offs2[n];
  int deg = (int)(offs2[n + 1] - off);
  if (deg == 0) return;

  const float* qkr = qkbuf + (size_t)n * 1920;
  float qk0[8], qk1[8], qk2[8], qk3[8];
  if (u < 48) {
    float4 a = *(const float4*)(qkr + o0);
    float4 b = *(const float4*)(qkr + o0 + 4);
    qk0[0]=a.x; qk0[1]=a.y; qk0[2]=a.z; qk0[3]=a.w;
    qk0[4]=b.x; qk0[5]=b.y; qk0[6]=b.z; qk0[7]=b.w;
  } else {
#pragma unroll
    for (int h = 0; h < 8; h++) qk0[h] = 0.f;
  }
  {
    float4 a = *(const float4*)(qkr + o1);
    float4 b = *(const float4*)(qkr + o1 + 4);
    qk1[0]=a.x; qk1[1]=a.y; qk1[2]=a.z; qk1[3]=a.w;
    qk1[4]=b.x; qk1[5]=b.y; qk1[6]=b.z; qk1[7]=b.w;
  }
  {
    float4 a = *(const float4*)(qkr + o2);
    float4 b = *(const float4*)(qkr + o2 + 4);
    qk2[0]=a.x; qk2[1]=a.y; qk2[2]=a.z; qk2[3]=a.w;
    qk2[4]=b.x; qk2[5]=b.y; qk2[6]=b.z; qk2[7]=b.w;
  }
  {
    float4 a = *(const float4*)(qkr + o3);
    float4 b = *(const float4*)(qkr + o3 + 4);
    qk3[0]=a.x; qk3[1]=a.y; qk3[2]=a.z; qk3[3]=a.w;
    qk3[4]=b.x; qk3[5]=b.y; qk3[6]=b.z; qk3[7]=b.w;
  }
  float s0 = sbuf[(size_t)n * 80 + idxA];
  float s1 = sbuf[(size_t)n * 80 + idxB];
  float s2 = sbuf[(size_t)n * 80 + idxC];

  int b0 = lane & 1, b1 = (lane >> 1) & 1, b2 = (lane >> 2) & 1;

  for (int t = 0; t < deg; t++) {
    unsigned e = sorted2[off + t];
    int dst = edge_index[(size_t)E + e];
    const float* drow = dbuf + (size_t)dst * 80;
    float xa = s0 + drow[idxA];
    float xb = s1 + drow[idxB];
    float xc = s2 + drow[idxC];
    const float* rr = rbf + (size_t)e * 16;
    float4 r0 = *(const float4*)(rr);
    float4 r1 = *(const float4*)(rr + 4);
    float4 r2 = *(const float4*)(rr + 8);
    float4 r3 = *(const float4*)(rr + 12);
    float4 y  = *(const float4*)(rsh + (size_t)e * 4);
    float wA = r0.x*wcA[0]+r0.y*wcA[1]+r0.z*wcA[2]+r0.w*wcA[3]
             + r1.x*wcA[4]+r1.y*wcA[5]+r1.z*wcA[6]+r1.w*wcA[7]
             + r2.x*wcA[8]+r2.y*wcA[9]+r2.z*wcA[10]+r2.w*wcA[11]
             + r3.x*wcA[12]+r3.y*wcA[13]+r3.z*wcA[14]+r3.w*wcA[15];
    float wB = r0.x*wcB[0]+r0.y*wcB[1]+r0.z*wcB[2]+r0.w*wcB[3]
             + r1.x*wcB[4]+r1.y*wcB[5]+r1.z*wcB[6]+r1.w*wcB[7]
             + r2.x*wcB[8]+r2.y*wcB[9]+r2.z*wcB[10]+r2.w*wcB[11]
             + r3.x*wcB[12]+r3.y*wcB[13]+r3.z*wcB[14]+r3.w*wcB[15];
    float cp0, c0, c1, c2;
    cp_own_build(u, xa, xb, xc, wA, wB, y.x, y.y, y.z, y.w, cp0, c0, c1, c2);

    float p[8];
#pragma unroll
    for (int h = 0; h < 8; h++)
      p[h] = qk0[h]*cp0 + qk1[h]*c0 + qk2[h]*c1 + qk3[h]*c2;
    float q4[4];
#pragma unroll
    for (int i = 0; i < 4; i++) {
      float mine = b0 ? p[2*i+1] : p[2*i];
      float send = b0 ? p[2*i]   : p[2*i+1];
      q4[i] = mine + __shfl_xor(send, 1);
    }
    float q2a, q2b;
    {
      float mine = b1 ? q4[1] : q4[0];
      float send = b1 ? q4[0] : q4[1];
      q2a = mine + __shfl_xor(send, 2);
      mine = b1 ? q4[3] : q4[2];
      send = b1 ? q4[2] : q4[3];
      q2b = mine + __shfl_xor(send, 2);
    }
    float mine = b2 ? q2b : q2a;
    float send = b2 ? q2a : q2b;
    float q1 = mine + __shfl_xor(send, 4);
    q1 += __shfl_xor(q1, 8);
    q1 += __shfl_xor(q1, 16);
    q1 += __shfl_xor(q1, 32);
    if (lane < 8) logits[(size_t)e * 8 + lane] = q1 * SCALE_ATT;
  }
}

// ---------------- per-(node,head) segment max ----------------
__global__ __launch_bounds__(256) void k_max(
    const float* __restrict__ logits,
    const unsigned* __restrict__ offs, const unsigned* __restrict__ sorted,
    float* __restrict__ mxbuf, int N) {
  int tid = threadIdx.x, wid = tid >> 6, lane = tid & 63;
  int n = blockIdx.x * 4 + wid;
  if (n >= N) return;
  unsigned off = offs[n];
  int deg = (int)(offs[n + 1] - off);
  float mx = -3.4e38f;
  for (int i = lane; i < deg * 8; i += 64) {
    unsigned e = sorted[off + (i >> 3)];
    mx = fmaxf(mx, logits[(size_t)e * 8 + (i & 7)]);
  }
  mx = fmaxf(mx, __shfl_xor(mx, 8));
  mx = fmaxf(mx, __shfl_xor(mx, 16));
  mx = fmaxf(mx, __shfl_xor(mx, 32));
  if (lane < 8) mxbuf[(size_t)n * 8 + lane] = mx;
}

// ---------------- dst-major aggregation: fence-free, two-pass softmax ----------
__global__ __launch_bounds__(256, 4) void k_agg(
    const float* __restrict__ rbf, const float* __restrict__ rsh,
    const int* __restrict__ edge_index,
    const float* __restrict__ W_rbf, const float* __restrict__ Wkv0,
    const float* __restrict__ Wkv1,
    const float* __restrict__ sbuf, const float* __restrict__ dbuf,
    const float* __restrict__ logits, const float* __restrict__ mxbuf,
    const unsigned* __restrict__ offs, const unsigned* __restrict__ sorted,
    float* __restrict__ mlbuf, int N, int E) {
  __shared__ float S[4 * 1952];
  int tid = threadIdx.x, wid = tid >> 6, lane = tid & 63;
  float* acpL = S + wid * 1952;
  int u = lane;
  bool cls0 = (u < 32);
  int tx = cls0 ? 0 : ((u < 48) ? u - 32 : u - 48);
  int idxA = cls0 ? u : 32 + 3 * tx;
  int idxB = cls0 ? u : idxA + 1;
  int idxC = cls0 ? u : idxA + 2;
  int colA = (u < 48) ? u : 48 + u;
  int colB = 48 + u;
  float wcA[16], wcB[16];
#pragma unroll
  for (int k = 0; k < 16; k++) {
    wcA[k] = W_rbf[k * 112 + colA];
    wcB[k] = W_rbf[k * 112 + colB];
  }

  int n = blockIdx.x * 4 + wid;
  if (n >= N) return;
  unsigned off = offs[n];
  int deg = (int)(offs[n + 1] - off);
  float* mlrow = mlbuf + (size_t)n * 640;
  if (deg == 0) {
#pragma unroll
    for (int g = 0; g < 10; g++) mlrow[g * 64 + lane] = 0.f;
    return;
  }

  float d0 = dbuf[(size_t)n * 80 + idxA];
  float d1 = dbuf[(size_t)n * 80 + idxB];
  float d2 = dbuf[(size_t)n * 80 + idxC];
  float4 mxa = *(const float4*)(mxbuf + (size_t)n * 8);
  float4 mxb = *(const float4*)(mxbuf + (size_t)n * 8 + 4);

  float acc0[8], acc1[8], acc2[8], acc3[8];
#pragma unroll
  for (int h = 0; h < 8; h++) { acc0[h]=0.f; acc1[h]=0.f; acc2[h]=0.f; acc3[h]=0.f; }
  float z_own = 0.f;

  for (int t = 0; t < deg; t++) {
    unsigned e = sorted[off + t];
    int src = edge_index[e];
    const float* srow = sbuf + (size_t)src * 80;
    float xa = srow[idxA] + d0;
    float xb = srow[idxB] + d1;
    float xc = srow[idxC] + d2;
    const float* rr = rbf + (size_t)e * 16;
    float4 r0 = *(const float4*)(rr);
    float4 r1 = *(const float4*)(rr + 4);
    float4 r2 = *(const float4*)(rr + 8);
    float4 r3 = *(const float4*)(rr + 12);
    float4 y  = *(const float4*)(rsh + (size_t)e * 4);
    float wA = r0.x*wcA[0]+r0.y*wcA[1]+r0.z*wcA[2]+r0.w*wcA[3]
             + r1.x*wcA[4]+r1.y*wcA[5]+r1.z*wcA[6]+r1.w*wcA[7]
             + r2.x*wcA[8]+r2.y*wcA[9]+r2.z*wcA[10]+r2.w*wcA[11]
             + r3.x*wcA[12]+r3.y*wcA[13]+r3.z*wcA[14]+r3.w*wcA[15];
    float wB = r0.x*wcB[0]+r0.y*wcB[1]+r0.z*wcB[2]+r0.w*wcB[3]
             + r1.x*wcB[4]+r1.y*wcB[5]+r1.z*wcB[6]+r1.w*wcB[7]
             + r2.x*wcB[8]+r2.y*wcB[9]+r2.z*wcB[10]+r2.w*wcB[11]
             + r3.x*wcB[12]+r3.y*wcB[13]+r3.z*wcB[14]+r3.w*wcB[15];
    float cp0, c0, c1, c2;
    cp_own_build(u, xa, xb, xc, wA, wB, y.x, y.y, y.z, y.w, cp0, c0, c1, c2);

    float4 lgA = *(const float4*)(logits + (size_t)e * 8);
    float4 lgB = *(const float4*)(logits + (size_t)e * 8 + 4);
    float aa[8];
    aa[0] = __expf(lgA.x - mxa.x); aa[1] = __expf(lgA.y - mxa.y);
    aa[2] = __expf(lgA.z - mxa.z); aa[3] = __expf(lgA.w - mxa.w);
    aa[4] = __expf(lgB.x - mxb.x); aa[5] = __expf(lgB.y - mxb.y);
    aa[6] = __expf(lgB.z - mxb.z); aa[7] = __expf(lgB.w - mxb.w);
    float aaz = (u & 4) ? ((u & 2) ? ((u & 1) ? aa[7] : aa[6])
                                   : ((u & 1) ? aa[5] : aa[4]))
                        : ((u & 2) ? ((u & 1) ? aa[3] : aa[2])
                                   : ((u & 1) ? aa[1] : aa[0]));
    z_own += aaz;
#pragma unroll
    for (int h = 0; h < 8; h++) {
      acc0[h] += aa[h] * cp0;
      acc1[h] += aa[h] * c0;
      acc2[h] += aa[h] * c1;
      acc3[h] += aa[h] * c2;
    }
  }

  int base = 48 + 3 * u;
#pragma unroll
  for (int h = 0; h < 8; h++) {
    if (u < 48) acpL[h * 241 + u] = acc0[h];
    acpL[h * 241 + base + 0] = acc1[h];
    acpL[h * 241 + base + 1] = acc2[h];
    acpL[h * 241 + base + 2] = acc3[h];
  }
  LDS_FENCE();

#pragma unroll
  for (int g = 0; g < 4; g++) {
    int col = g * 64 + lane;       // h*32+m
    int h2 = col >> 5;
    float a2 = 0.f;
#pragma unroll
    for (int k = 0; k < 48; k++) a2 += acpL[h2 * 241 + k] * Wkv0[k * 512 + 256 + col];
    float zz = __shfl(z_own, h2);
    mlrow[col] = a2 * INV_SQRT48 / (zz + 1e-16f);
  }
#pragma unroll
  for (int g = 0; g < 6; g++) {
    int pc = g * 64 + lane;        // p*3+c, p = h*16+u
    int p = pc / 3, c = pc - p * 3;
    int h2 = p >> 4;
    float a2 = 0.f;
#pragma unroll
    for (int w = 0; w < 64; w++)
      a2 += acpL[h2 * 241 + 48 + w * 3 + c] * Wkv1[w * 256 + 128 + p];
    float zz = __shfl(z_own, h2);
    mlrow[256 + pc] = a2 * 0.125f / (zz + 1e-16f);
  }
}

// ---------------- output projection + residual ----------------
__global__ __launch_bounds__(256) void k_out(
    const float* __restrict__ node, const float* __restrict__ mlbuf,
    const float* __restrict__ Wmsg0, const float* __restrict__ Wmsg1,
    float* __restrict__ out, int N) {
  __shared__ float mlw[4][640];
  int tid = threadIdx.x, wid = tid >> 6, lane = tid & 63;
  int n = blockIdx.x * 4 + wid;
  if (n >= N) return;
  const float* mlrow = mlbuf + (size_t)n * 640;
#pragma unroll
  for (int g = 0; g < 10; g++) mlw[wid][g * 64 + lane] = mlrow[g * 64 + lane];
  LDS_FENCE();
  const float* nrow = node + (size_t)n * 160;
  float* orow = out + (size_t)n * 160;
  {
    float a2 = 0.f;
#pragma unroll 8
    for (int j = 0; j < 256; j++) a2 += mlw[wid][j] * Wmsg0[j * 64 + lane];
    orow[lane] = nrow[lane] + a2 * 0.0625f;
  }
#pragma unroll
  for (int i0 = 0; i0 < 96; i0 += 64) {
    int i = i0 + lane;
    if (i < 96) {
      int v = i / 3, c = i - v * 3;
      float a2 = 0.f;
#pragma unroll 8
      for (int p = 0; p < 128; p++) a2 += mlw[wid][256 + p * 3 + c] * Wmsg1[p * 32 + v];
      orow[64 + i] = nrow[64 + i] + a2 * INV_SQRT128;
    }
  }
}

extern "C" void kernel_launch(void* const* d_in, const int* in_sizes, int n_in,
                              void* d_out, int out_size, void* d_ws, size_t ws_size,
                              hipStream_t stream) {
  (void)n_in; (void)out_size; (void)ws_size;
  const float* node   = (const float*)d_in[0];
  const float* rbf    = (const float*)d_in[1];
  const float* rsh    = (const float*)d_in[2];
  const int*   eidx   = (const int*)d_in[3];
  const float* gamma0 = (const float*)d_in[4];
  const float* gamma1 = (const float*)d_in[5];
  const float* Wq0    = (const float*)d_in[6];
  const float* Wq1    = (const float*)d_in[7];
  const float* Wsrc0  = (const float*)d_in[8];
  const float* Wsrc1  = (const float*)d_in[9];
  const float* Wdst0  = (const float*)d_in[10];
  const float* Wdst1  = (const float*)d_in[11];
  const float* W_rbf  = (const float*)d_in[12];
  const float* Wkv0   = (const float*)d_in[13];
  const float* Wkv1   = (const float*)d_in[14];
  const float* Wmsg0  = (const float*)d_in[15];
  const float* Wmsg1  = (const float*)d_in[16];
  float* out = (float*)d_out;

  int N = in_sizes[0] / 160;
  int E = in_sizes[3] / 2;

  unsigned* WS  = (unsigned*)d_ws;                        // 32*384 = 12288
  unsigned* WV  = WS + 12288;                             // 16*512 = 8192
  float* sbuf   = (float*)(WV + 8192);                    // N*80
  float* dbuf   = sbuf + (size_t)N * 80;                  // N*80
  float* qkbuf  = dbuf + (size_t)N * 80;                  // N*1920
  float* mlbuf  = qkbuf + (size_t)N * 1920;               // N*640
  float* hbuf   = mlbuf;                                  // alias: dead before k_agg
  float* logits = mlbuf + (size_t)N * 640;                // E*8
  float* mxbuf  = logits + (size_t)E * 8;                 // N*8
  unsigned* count   = (unsigned*)(mxbuf + (size_t)N * 8);   // N
  unsigned* offs    = count + N;                            // N+1
  unsigned* cursor  = offs + N + 1;                         // N
  unsigned* sorted  = cursor + N;                           // E
  unsigned* count2  = sorted + E;                           // N
  unsigned* offs2   = count2 + N;                           // N+1
  unsigned* cursor2 = offs2 + N + 1;                        // N
  unsigned* sorted2 = cursor2 + N;                          // E

  hipLaunchKernelGGL(init_count, dim3((N + 255) / 256), dim3(256), 0, stream,
                     count, count2, N);
  hipLaunchKernelGGL(k_hist, dim3((E + 255) / 256), dim3(256), 0, stream,
                     eidx, count, count2, E);
  hipLaunchKernelGGL(k_scan2, dim3(2), dim3(1024), 0, stream,
                     count, offs, cursor, count2, offs2, cursor2, N);
  hipLaunchKernelGGL(k_scatter, dim3((E + 255) / 256), dim3(256), 0, stream,
                     eidx, cursor, sorted, cursor2, sorted2, E);
  hipLaunchKernelGGL(k_wfold2, dim3(80), dim3(256), 0, stream,
                     Wq0, Wq1, Wkv0, Wkv1, WS, WV);
  hipLaunchKernelGGL(k_norm, dim3((N + 3) / 4), dim3(256), 0, stream,
                     node, gamma0, gamma1, Wsrc0, Wsrc1, Wdst0, Wdst1,
                     hbuf, sbuf, dbuf, N);
  hipLaunchKernelGGL(k_qk, dim3((N + 7) / 8), dim3(256), 0, stream,
                     hbuf, WS, WV, qkbuf, N);
  hipLaunchKernelGGL(k_logit, dim3((N + 3) / 4), dim3(256), 0, stream,
                     rbf, rsh, eidx, W_rbf, qkbuf, sbuf, dbuf,
                     offs2, sorted2, logits, N, E);
  hipLaunchKernelGGL(k_max, dim3((N + 3) / 4), dim3(256), 0, stream,
                     logits, offs, sorted, mxbuf, N);
  hipLaunchKernelGGL(k_agg, dim3((N + 3) / 4), dim3(256), 0, stream,
                     rbf, rsh, eidx, W_rbf, Wkv0, Wkv1, sbuf, dbuf, logits, mxbuf,
                     offs, sorted, mlbuf, N, E);
  hipLaunchKernelGGL(k_out, dim3((N + 3) / 4), dim3(256), 0, stream,
                     node, mlbuf, Wmsg0, Wmsg1, out, N);
}